// Round 6
// baseline (1144.784 us; speedup 1.0000x reference)
//
#include <hip/hip_runtime.h>
#include <math.h>

#define DD  128   // node channels
#define DEE 32    // edge channels

__device__ __forceinline__ float tanh_fast(float x) {
    // tanh(x) = 1 - 2/(e^{2x}+1); exp2-based, correct limits at +-inf
    float e = __builtin_amdgcn_exp2f(x * 2.885390082f);   // e^{2x}
    return 1.0f - 2.0f * __builtin_amdgcn_rcpf(e + 1.0f);
}

// =====================================================================
// Streaming fused GEMM: out[n][c] = post( in[n]@W[:,c] + bias[c] )
// W (128x128) in LDS; X 16-row tile, register-prefetch double-buffered.
// Thread: 2 rows x 4 cols. POST: 0=id, 1=tanh. BNSTAT: accumulate stats.
// nrows must be a multiple of 16 (50000 = 3125*16).
// =====================================================================
template<int POST, int BNSTAT>
__global__ __launch_bounds__(256) void gemm128_kernel(
    const float* __restrict__ in, const float* __restrict__ W,
    const float* __restrict__ bias, float* __restrict__ out, int nrows,
    float* __restrict__ bnsum, float* __restrict__ bnsumsq)
{
    __shared__ float Ws[DD * DD];       // 64 KB
    __shared__ float Xs[2][16 * DD];    // 2 x 8 KB
    __shared__ float ps[DD], psq[DD];

    const int tid = threadIdx.x;
    for (int i = tid; i < DD * DD / 4; i += 256)
        ((float4*)Ws)[i] = ((const float4*)W)[i];
    if constexpr (BNSTAT != 0) {
        if (tid < DD) { ps[tid] = 0.f; psq[tid] = 0.f; }
    }

    const int c0 = (tid & 31) * 4;
    const int r0 = tid >> 5;
    const int idx = tid * 8;          // flat offset in 16x128 tile
    const int ntiles = nrows >> 4;

    float bsum0=0.f,bsum1=0.f,bsum2=0.f,bsum3=0.f;
    float bsq0=0.f,bsq1=0.f,bsq2=0.f,bsq3=0.f;

    float4 bv = make_float4(0.f,0.f,0.f,0.f);
    if (bias) bv = *(const float4*)(bias + c0);

    int tile = blockIdx.x;
    bool have = tile < ntiles;
    float4 n0, n1;
    if (have) {
        const float* ip = in + ((size_t)tile << 4) * DD + idx;
        n0 = ((const float4*)ip)[0];
        n1 = ((const float4*)ip)[1];
    }
    __syncthreads();                  // Ws ready
    if (have) {
        *(float4*)&Xs[0][idx]     = n0;
        *(float4*)&Xs[0][idx + 4] = n1;
    }
    __syncthreads();

    int buf = 0;
    while (have) {
        // --- issue next tile's global loads (latency hidden under compute) ---
        const int next = tile + gridDim.x;
        const bool haveN = next < ntiles;
        if (haveN) {
            const float* ip = in + ((size_t)next << 4) * DD + idx;
            n0 = ((const float4*)ip)[0];
            n1 = ((const float4*)ip)[1];
        }

        // --- compute from Xs[buf] ---
        float acc00=0,acc01=0,acc02=0,acc03=0;
        float acc10=0,acc11=0,acc12=0,acc13=0;
        const float* xs = Xs[buf];
        #pragma unroll 4
        for (int k = 0; k < DD; k += 4) {
            float4 x0 = *(const float4*)&xs[r0 * DD + k];
            float4 x1 = *(const float4*)&xs[(r0 + 8) * DD + k];
            const float xs0[4] = {x0.x, x0.y, x0.z, x0.w};
            const float xs1[4] = {x1.x, x1.y, x1.z, x1.w};
            #pragma unroll
            for (int kk = 0; kk < 4; kk++) {
                float4 wv = *(const float4*)&Ws[(k + kk) * DD + c0];
                acc00 += xs0[kk]*wv.x; acc01 += xs0[kk]*wv.y;
                acc02 += xs0[kk]*wv.z; acc03 += xs0[kk]*wv.w;
                acc10 += xs1[kk]*wv.x; acc11 += xs1[kk]*wv.y;
                acc12 += xs1[kk]*wv.z; acc13 += xs1[kk]*wv.w;
            }
        }

        // --- epilogue ---
        float o00 = acc00 + bv.x, o01 = acc01 + bv.y, o02 = acc02 + bv.z, o03 = acc03 + bv.w;
        float o10 = acc10 + bv.x, o11 = acc11 + bv.y, o12 = acc12 + bv.z, o13 = acc13 + bv.w;
        if constexpr (POST == 1) {
            o00 = tanh_fast(o00); o01 = tanh_fast(o01); o02 = tanh_fast(o02); o03 = tanh_fast(o03);
            o10 = tanh_fast(o10); o11 = tanh_fast(o11); o12 = tanh_fast(o12); o13 = tanh_fast(o13);
        }
        const size_t row0 = ((size_t)tile << 4) + r0;
        *(float4*)(out + row0 * DD + c0)       = make_float4(o00,o01,o02,o03);
        *(float4*)(out + (row0 + 8) * DD + c0) = make_float4(o10,o11,o12,o13);
        if constexpr (BNSTAT != 0) {
            bsum0 += o00+o10; bsum1 += o01+o11; bsum2 += o02+o12; bsum3 += o03+o13;
            bsq0 += o00*o00+o10*o10; bsq1 += o01*o01+o11*o11;
            bsq2 += o02*o02+o12*o12; bsq3 += o03*o03+o13*o13;
        }

        // --- write prefetched tile to other buffer ---
        if (haveN) {
            *(float4*)&Xs[buf ^ 1][idx]     = n0;
            *(float4*)&Xs[buf ^ 1][idx + 4] = n1;
        }
        __syncthreads();
        buf ^= 1;
        tile = next;
        have = haveN;
    }

    if constexpr (BNSTAT != 0) {
        atomicAdd(&ps[c0+0], bsum0); atomicAdd(&ps[c0+1], bsum1);
        atomicAdd(&ps[c0+2], bsum2); atomicAdd(&ps[c0+3], bsum3);
        atomicAdd(&psq[c0+0], bsq0); atomicAdd(&psq[c0+1], bsq1);
        atomicAdd(&psq[c0+2], bsq2); atomicAdd(&psq[c0+3], bsq3);
        __syncthreads();
        if (tid < DD) {
            atomicAdd(&bnsum[tid], ps[tid]);
            atomicAdd(&bnsumsq[tid], psq[tid]);
        }
    }
}

// ============================ CSR sort ================================
__global__ __launch_bounds__(256) void hist_kernel(
    const int* __restrict__ dst, int* __restrict__ deg, int E)
{
    const int i = blockIdx.x * 256 + threadIdx.x;
    if (i < E) atomicAdd(&deg[dst[i]], 1);
}

__global__ __launch_bounds__(256) void scan1_kernel(
    const int* __restrict__ deg, int* __restrict__ excl,
    int* __restrict__ blksum, int N)
{
    __shared__ int s[256];
    const int tid = threadIdx.x;
    const int i = blockIdx.x * 256 + tid;
    const int v = (i < N) ? deg[i] : 0;
    s[tid] = v; __syncthreads();
    for (int off = 1; off < 256; off <<= 1) {
        int t = (tid >= off) ? s[tid - off] : 0;
        __syncthreads();
        s[tid] += t;
        __syncthreads();
    }
    if (i < N) excl[i] = s[tid] - v;
    if (tid == 255) blksum[blockIdx.x] = s[255];
}

__global__ __launch_bounds__(256) void scan2_kernel(int* __restrict__ blksum, int nblk)
{
    __shared__ int s[256];
    const int tid = threadIdx.x;
    const int v = (tid < nblk) ? blksum[tid] : 0;
    s[tid] = v; __syncthreads();
    for (int off = 1; off < 256; off <<= 1) {
        int t = (tid >= off) ? s[tid - off] : 0;
        __syncthreads();
        s[tid] += t;
        __syncthreads();
    }
    if (tid < nblk) blksum[tid] = s[tid] - v;   // in-place exclusive
}

__global__ __launch_bounds__(256) void scan3_kernel(
    int* __restrict__ rowptr, const int* __restrict__ blkoff,
    int* __restrict__ cursor, int N, int E)
{
    const int i = blockIdx.x * 256 + threadIdx.x;
    if (i < N) {
        const int r = rowptr[i] + blkoff[blockIdx.x];
        rowptr[i] = r;
        cursor[i] = r;
    }
    if (i == 0) rowptr[N] = E;
}

__global__ __launch_bounds__(256) void scatter_kernel(
    const int* __restrict__ dst, int* __restrict__ cursor,
    int* __restrict__ eidx, int E)
{
    const int i = blockIdx.x * 256 + threadIdx.x;
    if (i < E) {
        const int p = atomicAdd(&cursor[dst[i]], 1);
        eidx[p] = i;
    }
}

// =====================================================================
// Aggregation: one wave per dst node. W_edge in registers (64/lane).
// For each edge: normalize ea, project, m=tanh(h[src]+p), l=m.att,
// w=exp(l); accumulate w*m, w in registers. Epilogue writes
// pre[n] = (1+eps)*h[n] + acc/(den+1e-16) and denom[n].
// =====================================================================
__global__ __launch_bounds__(256, 4) void agg_kernel(
    const float* __restrict__ ea, const int* __restrict__ srcA,
    const int* __restrict__ eidx, const int* __restrict__ rowptr,
    const float* __restrict__ Wedge, const float* __restrict__ bedge,
    const float* __restrict__ att, const float* __restrict__ h,
    const float* __restrict__ epsp,
    float* __restrict__ pre, float* __restrict__ denom,
    float* __restrict__ wexp, int N)
{
    const int lane = threadIdx.x & 63;
    float we0[DEE], we1[DEE];
    #pragma unroll
    for (int k = 0; k < DEE; k++) {
        we0[k] = Wedge[k * DD + lane];
        we1[k] = Wedge[k * DD + 64 + lane];
    }
    const float be0 = bedge[lane], be1 = bedge[64 + lane];
    const float av0 = att[lane],   av1 = att[64 + lane];
    const float epsv = 1.0f + epsp[0];

    const int w  = (blockIdx.x * 256 + threadIdx.x) >> 6;
    const int nw = (gridDim.x * 256) >> 6;

    for (int n = w; n < N; n += nw) {
        const int r0 = rowptr[n], r1 = rowptr[n + 1];
        float acc0 = 0.f, acc1 = 0.f, den = 0.f;
        for (int j = r0; j < r1; j++) {
            const int e = eidx[j];
            float v = (lane < DEE) ? ea[(size_t)e * DEE + lane] : 0.f;
            float ss = v * v;
            ss += __shfl_xor(ss, 32); ss += __shfl_xor(ss, 16);
            ss += __shfl_xor(ss, 8);  ss += __shfl_xor(ss, 4);
            ss += __shfl_xor(ss, 2);  ss += __shfl_xor(ss, 1);
            const float inv = 1.0f / (sqrtf(ss) + 1e-8f);

            float p0 = be0, p1 = be1;
            #pragma unroll
            for (int k = 0; k < DEE; k++) {
                const float ek = __shfl(v, k) * inv;
                p0 += ek * we0[k];
                p1 += ek * we1[k];
            }

            const int s = srcA[e];
            const float m0 = tanh_fast(h[(size_t)s * DD + lane]      + p0);
            const float m1 = tanh_fast(h[(size_t)s * DD + 64 + lane] + p1);

            float l = m0 * av0 + m1 * av1;
            l += __shfl_xor(l, 32); l += __shfl_xor(l, 16);
            l += __shfl_xor(l, 8);  l += __shfl_xor(l, 4);
            l += __shfl_xor(l, 2);  l += __shfl_xor(l, 1);
            const float wgt = __builtin_amdgcn_exp2f(l * 1.44269504f);  // |l|<~20, safe

            if (lane == 0) wexp[e] = wgt;
            acc0 += wgt * m0; acc1 += wgt * m1; den += wgt;
        }
        const float invd = 1.0f / (den + 1e-16f);
        pre[(size_t)n * DD + lane]      = epsv * h[(size_t)n * DD + lane]      + acc0 * invd;
        pre[(size_t)n * DD + 64 + lane] = epsv * h[(size_t)n * DD + 64 + lane] + acc1 * invd;
        if (lane == 0) denom[n] = den;
    }
}

// attn[e] = wexp[e] / (denom[dst[e]] + 1e-16)
__global__ __launch_bounds__(256) void attn_kernel(
    const float* __restrict__ wexp, const int* __restrict__ dst,
    const float* __restrict__ denom, float* __restrict__ attn_out, int nedges)
{
    const int i = blockIdx.x * 256 + threadIdx.x;
    if (i < nedges) attn_out[i] = wexp[i] / (denom[dst[i]] + 1e-16f);
}

__global__ void bnfin_kernel(
    const float* __restrict__ bnsum, const float* __restrict__ bnsumsq,
    const float* __restrict__ gamma, const float* __restrict__ beta,
    float* __restrict__ scale, float* __restrict__ shift, float invn)
{
    const int c = threadIdx.x;
    if (c < DD) {
        const float mu  = bnsum[c] * invn;
        const float var = bnsumsq[c] * invn - mu * mu;
        const float a   = gamma[c] * rsqrtf(var + 1e-5f);
        scale[c] = a;
        shift[c] = beta[c] - mu * a;
    }
}

// z <- tanh(z*scale + shift), in place
__global__ __launch_bounds__(256) void bntrans_kernel(
    float* __restrict__ z, const float* __restrict__ sc,
    const float* __restrict__ sh, int nrows)
{
    __shared__ float s_sc[DD], s_sh[DD];
    if (threadIdx.x < DD) { s_sc[threadIdx.x] = sc[threadIdx.x]; s_sh[threadIdx.x] = sh[threadIdx.x]; }
    __syncthreads();
    const size_t total  = (size_t)nrows * DD;
    const size_t stride = (size_t)gridDim.x * 1024;
    for (size_t i = ((size_t)blockIdx.x * 256 + threadIdx.x) * 4; i < total; i += stride) {
        float4 v = *(float4*)(z + i);
        const int c = (int)(i & (DD - 1));
        v.x = tanh_fast(v.x * s_sc[c]     + s_sh[c]);
        v.y = tanh_fast(v.y * s_sc[c + 1] + s_sh[c + 1]);
        v.z = tanh_fast(v.z * s_sc[c + 2] + s_sh[c + 2]);
        v.w = tanh_fast(v.w * s_sc[c + 3] + s_sh[c + 3]);
        *(float4*)(z + i) = v;
    }
}

extern "C" void kernel_launch(void* const* d_in, const int* in_sizes, int n_in,
                              void* d_out, int out_size, void* d_ws, size_t ws_size,
                              hipStream_t stream) {
    const float* x      = (const float*)d_in[0];
    const float* eattr  = (const float*)d_in[1];
    const int*   ei     = (const int*)  d_in[2];
    const float* W_init = (const float*)d_in[3];
    const float* W_edge = (const float*)d_in[4];
    const float* b_edge = (const float*)d_in[5];
    const float* attv   = (const float*)d_in[6];
    const float* eps    = (const float*)d_in[7];
    const float* W_u1   = (const float*)d_in[8];
    const float* b_u1   = (const float*)d_in[9];
    const float* W_u2   = (const float*)d_in[10];
    const float* b_u2   = (const float*)d_in[11];
    const float* W_o1   = (const float*)d_in[12];
    const float* b_o1   = (const float*)d_in[13];
    const float* gamma  = (const float*)d_in[14];
    const float* beta   = (const float*)d_in[15];
    const float* W_o2   = (const float*)d_in[16];
    const float* b_o2   = (const float*)d_in[17];

    const int N = in_sizes[0] / DD;     // 50000
    const int E = in_sizes[2] / 2;      // 800000
    const size_t ND = (size_t)N * DD;

    float* out      = (float*)d_out;
    float* attn_out = out + ND;

    // workspace layout (floats): h | pre | tbuf | denom | wexp | bn(4x128)
    float* ws    = (float*)d_ws;
    float* h     = ws;
    float* pre   = ws + ND;
    float* tbuf  = ws + 2 * ND;
    float* denom = ws + 3 * ND;
    float* wexp  = denom + N;
    float* bnsum = wexp + E;
    float* bnsq  = bnsum + DD;
    float* bnsc  = bnsq + DD;
    float* bnsh  = bnsc + DD;
    // int aliases (dead before the float owner is written):
    int* deg    = (int*)pre;            // hist/scan input; dead after scan1
    int* cursor = (int*)pre + N;        // dead after scatter; pre written in agg
    int* eidx   = (int*)tbuf;           // E ints; dead after agg; tbuf written after
    int* rowptr = (int*)tbuf + E;       // N+1 ints; dead after agg
    int* blksum = (int*)tbuf + E + N + 1; // 256 ints
    float* ubuf = pre;                  // pre dead after GIN gemm
    float* zbuf = h;                    // h dead after agg

    const int* srcp = ei;
    const int* dstp = ei + E;

    hipMemsetAsync(deg, 0, (size_t)N * sizeof(int), stream);
    hipMemsetAsync(bnsum, 0, 2 * DD * sizeof(float), stream);

    const int gemm_grid = 512;
    const int nblkN = (N + 255) / 256;       // 196
    const int nblkE = (E + 255) / 256;       // 3125
    dim3 blk(256);

    // h = x @ W_init
    gemm128_kernel<0,0><<<gemm_grid, blk, 0, stream>>>(
        x, W_init, nullptr, h, N, nullptr, nullptr);

    // CSR sort by dst
    hist_kernel<<<nblkE, blk, 0, stream>>>(dstp, deg, E);
    scan1_kernel<<<nblkN, blk, 0, stream>>>(deg, rowptr, blksum, N);
    scan2_kernel<<<1, blk, 0, stream>>>(blksum, nblkN);
    scan3_kernel<<<nblkN, blk, 0, stream>>>(rowptr, blksum, cursor, N, E);
    scatter_kernel<<<nblkE, blk, 0, stream>>>(dstp, cursor, eidx, E);

    // aggregation (atomic-free) + GIN pre-activation
    agg_kernel<<<1024, blk, 0, stream>>>(
        eattr, srcp, eidx, rowptr, W_edge, b_edge, attv, h, eps,
        pre, denom, wexp, N);

    // attn output
    attn_kernel<<<nblkE, blk, 0, stream>>>(wexp, dstp, denom, attn_out, E);

    // t = tanh(pre @ W_u1 + b_u1)
    gemm128_kernel<1,0><<<gemm_grid, blk, 0, stream>>>(
        pre, W_u1, b_u1, tbuf, N, nullptr, nullptr);

    // u = t @ W_u2 + b_u2
    gemm128_kernel<0,0><<<gemm_grid, blk, 0, stream>>>(
        tbuf, W_u2, b_u2, ubuf, N, nullptr, nullptr);

    // z = u @ W_o1 + b_o1  (+ BN stats)
    gemm128_kernel<0,1><<<gemm_grid, blk, 0, stream>>>(
        ubuf, W_o1, b_o1, zbuf, N, bnsum, bnsq);

    // BN finalize + in-place transform tanh(z*a+b)
    bnfin_kernel<<<1, DD, 0, stream>>>(bnsum, bnsq, gamma, beta, bnsc, bnsh, 1.0f / (float)N);
    bntrans_kernel<<<2048, blk, 0, stream>>>(zbuf, bnsc, bnsh, N);

    // out = zt @ W_o2 + b_o2
    gemm128_kernel<0,0><<<gemm_grid, blk, 0, stream>>>(
        zbuf, W_o2, b_o2, out, N, nullptr, nullptr);
}

// Round 8
// 812.400 us; speedup vs baseline: 1.4091x; 1.4091x over previous
//
#include <hip/hip_runtime.h>
#include <math.h>

#define DD  128   // node channels
#define DEE 32    // edge channels

__device__ __forceinline__ float tanh_fast(float x) {
    // tanh(x) = 1 - 2/(e^{2x}+1); exp2-based, correct limits at +-inf
    float e = __builtin_amdgcn_exp2f(x * 2.885390082f);   // e^{2x}
    return 1.0f - 2.0f * __builtin_amdgcn_rcpf(e + 1.0f);
}

// =====================================================================
// Streaming fused GEMM: out[n][c] = post( in[n]@W[:,c] + bias[c] )
// W (128x128) in LDS; X 16-row tile single-buffered (73 KB -> 2 blk/CU).
// Thread: 2 rows x 4 cols. POST: 0=id, 1=tanh. BNSTAT: accumulate stats.
// =====================================================================
template<int POST, int BNSTAT>
__global__ __launch_bounds__(256) void gemm128_kernel(
    const float* __restrict__ in, const float* __restrict__ W,
    const float* __restrict__ bias, float* __restrict__ out, int nrows,
    float* __restrict__ bnsum, float* __restrict__ bnsumsq)
{
    __shared__ float Ws[DD * DD];      // 64 KB
    __shared__ float Xs[16 * DD];      // 8 KB
    __shared__ float ps[DD], psq[DD];  // 1 KB

    const int tid = threadIdx.x;
    for (int i = tid; i < DD * DD / 4; i += 256)
        ((float4*)Ws)[i] = ((const float4*)W)[i];
    if constexpr (BNSTAT != 0) {
        if (tid < DD) { ps[tid] = 0.f; psq[tid] = 0.f; }
    }
    __syncthreads();

    const int c0 = (tid & 31) * 4;
    const int r0 = tid >> 5;
    const int idx = tid * 8;
    const int ntiles = (nrows + 15) >> 4;

    float bsum0=0.f,bsum1=0.f,bsum2=0.f,bsum3=0.f;
    float bsq0=0.f,bsq1=0.f,bsq2=0.f,bsq3=0.f;

    float4 bv = make_float4(0.f,0.f,0.f,0.f);
    if (bias) bv = *(const float4*)(bias + c0);

    for (int tile = blockIdx.x; tile < ntiles; tile += gridDim.x) {
        const int row_base = tile << 4;
        {
            const int r   = idx >> 7;
            const int k0  = idx & 127;
            const int row = row_base + r;
            float4 v0 = make_float4(0.f,0.f,0.f,0.f);
            float4 v1 = make_float4(0.f,0.f,0.f,0.f);
            if (row < nrows) {
                const float* ip = in + (size_t)row * DD + k0;
                v0 = ((const float4*)ip)[0];
                v1 = ((const float4*)ip)[1];
            }
            *(float4*)&Xs[idx]     = v0;
            *(float4*)&Xs[idx + 4] = v1;
        }
        __syncthreads();

        float acc00=0,acc01=0,acc02=0,acc03=0;
        float acc10=0,acc11=0,acc12=0,acc13=0;
        #pragma unroll 4
        for (int k = 0; k < DD; k += 4) {
            float4 x0 = *(const float4*)&Xs[r0 * DD + k];
            float4 x1 = *(const float4*)&Xs[(r0 + 8) * DD + k];
            const float xs0[4] = {x0.x, x0.y, x0.z, x0.w};
            const float xs1[4] = {x1.x, x1.y, x1.z, x1.w};
            #pragma unroll
            for (int kk = 0; kk < 4; kk++) {
                float4 wv = *(const float4*)&Ws[(k + kk) * DD + c0];
                acc00 += xs0[kk]*wv.x; acc01 += xs0[kk]*wv.y;
                acc02 += xs0[kk]*wv.z; acc03 += xs0[kk]*wv.w;
                acc10 += xs1[kk]*wv.x; acc11 += xs1[kk]*wv.y;
                acc12 += xs1[kk]*wv.z; acc13 += xs1[kk]*wv.w;
            }
        }

        float o00 = acc00 + bv.x, o01 = acc01 + bv.y, o02 = acc02 + bv.z, o03 = acc03 + bv.w;
        float o10 = acc10 + bv.x, o11 = acc11 + bv.y, o12 = acc12 + bv.z, o13 = acc13 + bv.w;
        if constexpr (POST == 1) {
            o00 = tanh_fast(o00); o01 = tanh_fast(o01); o02 = tanh_fast(o02); o03 = tanh_fast(o03);
            o10 = tanh_fast(o10); o11 = tanh_fast(o11); o12 = tanh_fast(o12); o13 = tanh_fast(o13);
        }
        const int row0 = row_base + r0;
        const int row1 = row0 + 8;
        if (row0 < nrows) {
            *(float4*)(out + (size_t)row0 * DD + c0) = make_float4(o00,o01,o02,o03);
            if constexpr (BNSTAT != 0) {
                bsum0 += o00; bsum1 += o01; bsum2 += o02; bsum3 += o03;
                bsq0 += o00*o00; bsq1 += o01*o01; bsq2 += o02*o02; bsq3 += o03*o03;
            }
        }
        if (row1 < nrows) {
            *(float4*)(out + (size_t)row1 * DD + c0) = make_float4(o10,o11,o12,o13);
            if constexpr (BNSTAT != 0) {
                bsum0 += o10; bsum1 += o11; bsum2 += o12; bsum3 += o13;
                bsq0 += o10*o10; bsq1 += o11*o11; bsq2 += o12*o12; bsq3 += o13*o13;
            }
        }
        __syncthreads();
    }

    if constexpr (BNSTAT != 0) {
        atomicAdd(&ps[c0+0], bsum0); atomicAdd(&ps[c0+1], bsum1);
        atomicAdd(&ps[c0+2], bsum2); atomicAdd(&ps[c0+3], bsum3);
        atomicAdd(&psq[c0+0], bsq0); atomicAdd(&psq[c0+1], bsq1);
        atomicAdd(&psq[c0+2], bsq2); atomicAdd(&psq[c0+3], bsq3);
        __syncthreads();
        if (tid < DD) {
            atomicAdd(&bnsum[tid], ps[tid]);
            atomicAdd(&bnsumsq[tid], psq[tid]);
        }
    }
}

// ============================ CSR sort ================================
__global__ __launch_bounds__(256) void hist_kernel(
    const int* __restrict__ dst, int* __restrict__ deg, int E)
{
    const int i = blockIdx.x * 256 + threadIdx.x;
    if (i < E) atomicAdd(&deg[dst[i]], 1);
}

__global__ __launch_bounds__(256) void scan1_kernel(
    const int* __restrict__ deg, int* __restrict__ excl,
    int* __restrict__ blksum, int N)
{
    __shared__ int s[256];
    const int tid = threadIdx.x;
    const int i = blockIdx.x * 256 + tid;
    const int v = (i < N) ? deg[i] : 0;
    s[tid] = v; __syncthreads();
    for (int off = 1; off < 256; off <<= 1) {
        int t = (tid >= off) ? s[tid - off] : 0;
        __syncthreads();
        s[tid] += t;
        __syncthreads();
    }
    if (i < N) excl[i] = s[tid] - v;
    if (tid == 255) blksum[blockIdx.x] = s[255];
}

__global__ __launch_bounds__(256) void scan2_kernel(int* __restrict__ blksum, int nblk)
{
    __shared__ int s[256];
    const int tid = threadIdx.x;
    const int v = (tid < nblk) ? blksum[tid] : 0;
    s[tid] = v; __syncthreads();
    for (int off = 1; off < 256; off <<= 1) {
        int t = (tid >= off) ? s[tid - off] : 0;
        __syncthreads();
        s[tid] += t;
        __syncthreads();
    }
    if (tid < nblk) blksum[tid] = s[tid] - v;   // in-place exclusive
}

__global__ __launch_bounds__(256) void scan3_kernel(
    int* __restrict__ rowptr, const int* __restrict__ blkoff,
    int* __restrict__ cursor, int N, int E)
{
    const int i = blockIdx.x * 256 + threadIdx.x;
    if (i < N) {
        const int r = rowptr[i] + blkoff[blockIdx.x];
        rowptr[i] = r;
        cursor[i] = r;
    }
    if (i == 0) rowptr[N] = E;
}

__global__ __launch_bounds__(256) void scatter_kernel(
    const int* __restrict__ dst, int* __restrict__ cursor,
    int* __restrict__ eidx, int E)
{
    const int i = blockIdx.x * 256 + threadIdx.x;
    if (i < E) {
        const int p = atomicAdd(&cursor[dst[i]], 1);
        eidx[p] = i;
    }
}

// =====================================================================
// Aggregation: one wave per dst node (grid-stride over 25k waves).
// Wave-uniform edge id -> ea row read as SCALAR loads (no broadcasts);
// W_edge pinned in VGPRs (64/lane) via asm barrier; h-gather hoisted
// above the projection so its latency hides under compute.
// =====================================================================
__global__ __launch_bounds__(256, 4) void agg_kernel(
    const float* __restrict__ ea, const int* __restrict__ srcA,
    const int* __restrict__ eidx, const int* __restrict__ rowptr,
    const float* __restrict__ Wedge, const float* __restrict__ bedge,
    const float* __restrict__ att, const float* __restrict__ h,
    const float* __restrict__ epsp,
    float* __restrict__ pre, float* __restrict__ denom,
    float* __restrict__ wexp, int N)
{
    const int lane = threadIdx.x & 63;
    float we0[DEE], we1[DEE];
    #pragma unroll
    for (int k = 0; k < DEE; k++) {
        we0[k] = Wedge[k * DD + lane];
        we1[k] = Wedge[k * DD + 64 + lane];
    }
    // pin the weight cache in VGPRs (defeat rematerialization)
    #pragma unroll
    for (int k = 0; k < DEE; k++) {
        asm volatile("" : "+v"(we0[k]), "+v"(we1[k]));
    }
    const float be0 = bedge[lane], be1 = bedge[64 + lane];
    const float av0 = att[lane],   av1 = att[64 + lane];
    const float epsv = 1.0f + epsp[0];

    // force wave-uniformity so downstream index loads scalarize
    const int w  = __builtin_amdgcn_readfirstlane((blockIdx.x * 256 + threadIdx.x) >> 6);
    const int nw = (gridDim.x * 256) >> 6;

    for (int n = w; n < N; n += nw) {
        const int r0 = rowptr[n], r1 = rowptr[n + 1];
        float acc0 = 0.f, acc1 = 0.f, den = 0.f;
        for (int j = r0; j < r1; j++) {
            const int e = eidx[j];        // wave-uniform -> s_load
            const int s = srcA[e];        // wave-uniform -> s_load

            // issue the h-gather early; latency hides under projection
            const float h0 = h[(size_t)s * DD + lane];
            const float h1 = h[(size_t)s * DD + 64 + lane];

            // per-lane ea copy for the norm reduce (dup across halves)
            const float v = ea[(size_t)e * DEE + (lane & 31)];
            float ss = v * v;
            ss += __shfl_xor(ss, 16); ss += __shfl_xor(ss, 8);
            ss += __shfl_xor(ss, 4);  ss += __shfl_xor(ss, 2);
            ss += __shfl_xor(ss, 1);
            const float inv = 1.0f / (sqrtf(ss) + 1e-8f);

            // projection via wave-uniform scalar ea values (s_load + SGPR FMA)
            float q0 = 0.f, q1 = 0.f;
            const float* er = ea + (size_t)e * DEE;
            #pragma unroll
            for (int k = 0; k < DEE; k++) {
                const float ek = er[k];   // uniform -> scalar operand
                q0 += ek * we0[k];
                q1 += ek * we1[k];
            }

            const float m0 = tanh_fast(h0 + be0 + q0 * inv);
            const float m1 = tanh_fast(h1 + be1 + q1 * inv);

            float l = m0 * av0 + m1 * av1;
            l += __shfl_xor(l, 32); l += __shfl_xor(l, 16);
            l += __shfl_xor(l, 8);  l += __shfl_xor(l, 4);
            l += __shfl_xor(l, 2);  l += __shfl_xor(l, 1);
            const float wgt = __builtin_amdgcn_exp2f(l * 1.44269504f);  // |l|<~20

            if (lane == 0) wexp[e] = wgt;
            acc0 += wgt * m0; acc1 += wgt * m1; den += wgt;
        }
        const float invd = 1.0f / (den + 1e-16f);
        pre[(size_t)n * DD + lane]      = epsv * h[(size_t)n * DD + lane]      + acc0 * invd;
        pre[(size_t)n * DD + 64 + lane] = epsv * h[(size_t)n * DD + 64 + lane] + acc1 * invd;
        if (lane == 0) denom[n] = den;
    }
}

// attn[e] = wexp[e] / (denom[dst[e]] + 1e-16)
__global__ __launch_bounds__(256) void attn_kernel(
    const float* __restrict__ wexp, const int* __restrict__ dst,
    const float* __restrict__ denom, float* __restrict__ attn_out, int nedges)
{
    const int i = blockIdx.x * 256 + threadIdx.x;
    if (i < nedges) attn_out[i] = wexp[i] / (denom[dst[i]] + 1e-16f);
}

__global__ void bnfin_kernel(
    const float* __restrict__ bnsum, const float* __restrict__ bnsumsq,
    const float* __restrict__ gamma, const float* __restrict__ beta,
    float* __restrict__ scale, float* __restrict__ shift, float invn)
{
    const int c = threadIdx.x;
    if (c < DD) {
        const float mu  = bnsum[c] * invn;
        const float var = bnsumsq[c] * invn - mu * mu;
        const float a   = gamma[c] * rsqrtf(var + 1e-5f);
        scale[c] = a;
        shift[c] = beta[c] - mu * a;
    }
}

// z <- tanh(z*scale + shift), in place
__global__ __launch_bounds__(256) void bntrans_kernel(
    float* __restrict__ z, const float* __restrict__ sc,
    const float* __restrict__ sh, int nrows)
{
    __shared__ float s_sc[DD], s_sh[DD];
    if (threadIdx.x < DD) { s_sc[threadIdx.x] = sc[threadIdx.x]; s_sh[threadIdx.x] = sh[threadIdx.x]; }
    __syncthreads();
    const size_t total  = (size_t)nrows * DD;
    const size_t stride = (size_t)gridDim.x * 1024;
    for (size_t i = ((size_t)blockIdx.x * 256 + threadIdx.x) * 4; i < total; i += stride) {
        float4 v = *(float4*)(z + i);
        const int c = (int)(i & (DD - 1));
        v.x = tanh_fast(v.x * s_sc[c]     + s_sh[c]);
        v.y = tanh_fast(v.y * s_sc[c + 1] + s_sh[c + 1]);
        v.z = tanh_fast(v.z * s_sc[c + 2] + s_sh[c + 2]);
        v.w = tanh_fast(v.w * s_sc[c + 3] + s_sh[c + 3]);
        *(float4*)(z + i) = v;
    }
}

extern "C" void kernel_launch(void* const* d_in, const int* in_sizes, int n_in,
                              void* d_out, int out_size, void* d_ws, size_t ws_size,
                              hipStream_t stream) {
    const float* x      = (const float*)d_in[0];
    const float* eattr  = (const float*)d_in[1];
    const int*   ei     = (const int*)  d_in[2];
    const float* W_init = (const float*)d_in[3];
    const float* W_edge = (const float*)d_in[4];
    const float* b_edge = (const float*)d_in[5];
    const float* attv   = (const float*)d_in[6];
    const float* eps    = (const float*)d_in[7];
    const float* W_u1   = (const float*)d_in[8];
    const float* b_u1   = (const float*)d_in[9];
    const float* W_u2   = (const float*)d_in[10];
    const float* b_u2   = (const float*)d_in[11];
    const float* W_o1   = (const float*)d_in[12];
    const float* b_o1   = (const float*)d_in[13];
    const float* gamma  = (const float*)d_in[14];
    const float* beta   = (const float*)d_in[15];
    const float* W_o2   = (const float*)d_in[16];
    const float* b_o2   = (const float*)d_in[17];

    const int N = in_sizes[0] / DD;     // 50000
    const int E = in_sizes[2] / 2;      // 800000
    const size_t ND = (size_t)N * DD;

    float* out      = (float*)d_out;
    float* attn_out = out + ND;

    // workspace layout (floats): h | pre | tbuf | denom | wexp | bn(4x128)
    float* ws    = (float*)d_ws;
    float* h     = ws;
    float* pre   = ws + ND;
    float* tbuf  = ws + 2 * ND;
    float* denom = ws + 3 * ND;
    float* wexp  = denom + N;
    float* bnsum = wexp + E;
    float* bnsq  = bnsum + DD;
    float* bnsc  = bnsq + DD;
    float* bnsh  = bnsc + DD;
    // int aliases (dead before the float owner is written):
    int* deg    = (int*)pre;              // dead after scan1
    int* cursor = (int*)pre + N;          // dead after scatter
    int* eidx   = (int*)tbuf;             // E ints; dead after agg
    int* rowptr = (int*)tbuf + E;         // N+1 ints; dead after agg
    int* blksum = (int*)tbuf + E + N + 1; // 256 ints
    float* ubuf = pre;                    // pre dead after GIN gemm
    float* zbuf = h;                      // h dead after agg

    const int* srcp = ei;
    const int* dstp = ei + E;

    hipMemsetAsync(deg, 0, (size_t)N * sizeof(int), stream);
    hipMemsetAsync(bnsum, 0, 2 * DD * sizeof(float), stream);

    const int gemm_grid = 512;
    const int nblkN = (N + 255) / 256;       // 196
    const int nblkE = (E + 255) / 256;       // 3125
    dim3 blk(256);

    // h = x @ W_init
    gemm128_kernel<0,0><<<gemm_grid, blk, 0, stream>>>(
        x, W_init, nullptr, h, N, nullptr, nullptr);

    // CSR sort by dst
    hist_kernel<<<nblkE, blk, 0, stream>>>(dstp, deg, E);
    scan1_kernel<<<nblkN, blk, 0, stream>>>(deg, rowptr, blksum, N);
    scan2_kernel<<<1, blk, 0, stream>>>(blksum, nblkN);
    scan3_kernel<<<nblkN, blk, 0, stream>>>(rowptr, blksum, cursor, N, E);
    scatter_kernel<<<nblkE, blk, 0, stream>>>(dstp, cursor, eidx, E);

    // aggregation (atomic-free) + GIN pre-activation
    agg_kernel<<<6250, blk, 0, stream>>>(
        eattr, srcp, eidx, rowptr, W_edge, b_edge, attv, h, eps,
        pre, denom, wexp, N);

    // attn output
    attn_kernel<<<nblkE, blk, 0, stream>>>(wexp, dstp, denom, attn_out, E);

    // t = tanh(pre @ W_u1 + b_u1)
    gemm128_kernel<1,0><<<gemm_grid, blk, 0, stream>>>(
        pre, W_u1, b_u1, tbuf, N, nullptr, nullptr);

    // u = t @ W_u2 + b_u2
    gemm128_kernel<0,0><<<gemm_grid, blk, 0, stream>>>(
        tbuf, W_u2, b_u2, ubuf, N, nullptr, nullptr);

    // z = u @ W_o1 + b_o1  (+ BN stats)
    gemm128_kernel<0,1><<<gemm_grid, blk, 0, stream>>>(
        ubuf, W_o1, b_o1, zbuf, N, bnsum, bnsq);

    // BN finalize + in-place transform tanh(z*a+b)
    bnfin_kernel<<<1, DD, 0, stream>>>(bnsum, bnsq, gamma, beta, bnsc, bnsh, 1.0f / (float)N);
    bntrans_kernel<<<2048, blk, 0, stream>>>(zbuf, bnsc, bnsh, N);

    // out = zt @ W_o2 + b_o2
    gemm128_kernel<0,0><<<gemm_grid, blk, 0, stream>>>(
        zbuf, W_o2, b_o2, out, N, nullptr, nullptr);
}